// Round 1
// baseline (519.039 us; speedup 1.0000x reference)
//
#include <hip/hip_runtime.h>
#include <math.h>

#define IM 64
#define NBATCH 256
#define NS 2
#define NP 2
#define HID 64
#define THREADS 256
#define TILES ((IM*IM)/THREADS)   // 16 blocks per batch image

__global__ __launch_bounds__(THREADS, 2) void genmodel_kernel(
    const int* __restrict__ program_id,
    const int* __restrict__ shape_ids,
    const float* __restrict__ raw_positions,
    const float* __restrict__ g_w0, const float* __restrict__ g_b0,
    const float* __restrict__ g_w1, const float* __restrict__ g_b1,
    const float* __restrict__ g_w2, const float* __restrict__ g_b2,
    const float* __restrict__ g_w3, const float* __restrict__ g_b3,
    const float* __restrict__ g_lmr,
    float* __restrict__ out)
{
    // Stage the two 64x64 weight matrices for both programs in LDS (64 KB).
    __shared__ float s_w1[NP*HID*HID];
    __shared__ float s_w2[NP*HID*HID];

    const int tid = threadIdx.x;
    #pragma unroll
    for (int r = 0; r < (NP*HID*HID/4)/THREADS; ++r) {
        int idx = r*THREADS + tid;
        ((float4*)s_w1)[idx] = ((const float4*)g_w1)[idx];
        ((float4*)s_w2)[idx] = ((const float4*)g_w2)[idx];
    }
    __syncthreads();

    const int b = blockIdx.x / TILES;
    const int n = (blockIdx.x % TILES) * THREADS + tid;   // pixel index in image
    const int row = n >> 6, col = n & 63;
    const float cx = -1.0f + (2.0f/63.0f) * (float)col;
    const float cy = -1.0f + (2.0f/63.0f) * (float)row;

    float p0 = 0.0f, p1 = 0.0f;

    #pragma unroll 1            // keep one copy of the MLP code (code size)
    for (int s = 0; s < NS; ++s) {
        const int pg = __builtin_amdgcn_readfirstlane(shape_ids[b*NS + s]);
        const float rx = raw_positions[(b*NS+s)*2 + 0];
        const float ry = raw_positions[(b*NS+s)*2 + 1];
        const float posx = 1.0f/(1.0f + expf(-rx)) - 0.5f;
        const float posy = 1.0f/(1.0f + expf(-ry)) - 0.5f;
        const float dx = cx - posx;
        const float dy = cy - posy;
        const float theta = atan2f(dy, dx);

        const float* w0  = g_w0 + pg*HID;
        const float* bb0 = g_b0 + pg*HID;
        const float* bb1 = g_b1 + pg*HID;
        const float* bb2 = g_b2 + pg*HID;
        const float* w3  = g_w3 + pg*HID;
        const float bb3  = g_b3[pg];
        const float lm   = g_lmr[pg];

        float h[HID], a[HID];
        // layer 0: 1 -> 64
        #pragma unroll
        for (int o = 0; o < HID; ++o)
            h[o] = fmaxf(fmaf(theta, w0[o], bb0[o]), 0.0f);

        // layer 1: 64 -> 64   (a = relu(h @ W1 + b1))
        #pragma unroll
        for (int o = 0; o < HID; ++o) a[o] = bb1[o];
        const float4* W1 = (const float4*)(s_w1 + pg*HID*HID);
        #pragma unroll
        for (int i = 0; i < HID; ++i) {
            const float hi = h[i];
            #pragma unroll
            for (int o4 = 0; o4 < HID/4; ++o4) {
                float4 w = W1[i*(HID/4) + o4];   // wave-uniform addr -> LDS broadcast
                a[o4*4+0] = fmaf(hi, w.x, a[o4*4+0]);
                a[o4*4+1] = fmaf(hi, w.y, a[o4*4+1]);
                a[o4*4+2] = fmaf(hi, w.z, a[o4*4+2]);
                a[o4*4+3] = fmaf(hi, w.w, a[o4*4+3]);
            }
        }
        #pragma unroll
        for (int o = 0; o < HID; ++o) a[o] = fmaxf(a[o], 0.0f);

        // layer 2: 64 -> 64   (h = a @ W2 + b2; relu folded into head)
        #pragma unroll
        for (int o = 0; o < HID; ++o) h[o] = bb2[o];
        const float4* W2 = (const float4*)(s_w2 + pg*HID*HID);
        #pragma unroll
        for (int i = 0; i < HID; ++i) {
            const float ai = a[i];
            #pragma unroll
            for (int o4 = 0; o4 < HID/4; ++o4) {
                float4 w = W2[i*(HID/4) + o4];
                h[o4*4+0] = fmaf(ai, w.x, h[o4*4+0]);
                h[o4*4+1] = fmaf(ai, w.y, h[o4*4+1]);
                h[o4*4+2] = fmaf(ai, w.z, h[o4*4+2]);
                h[o4*4+3] = fmaf(ai, w.w, h[o4*4+3]);
            }
        }

        // head: 64 -> 1
        float t0=0.f, t1=0.f, t2=0.f, t3=0.f;
        #pragma unroll
        for (int i = 0; i < HID; i += 4) {
            t0 = fmaf(fmaxf(h[i+0],0.f), w3[i+0], t0);
            t1 = fmaf(fmaxf(h[i+1],0.f), w3[i+1], t1);
            t2 = fmaf(fmaxf(h[i+2],0.f), w3[i+2], t2);
            t3 = fmaf(fmaxf(h[i+3],0.f), w3[i+3], t3);
        }
        const float ov = bb3 + ((t0+t1)+(t2+t3));

        const float mult  = expf(lm);
        const float r2    = sqrtf(dx*dx + dy*dy);
        const float logit = mult * (expf(ov) - r2);
        const float p     = 1.0f / (1.0f + expf(-logit));
        if (s == 0) p0 = p; else p1 = p;
    }

    const int pid = program_id[b];
    float res;
    if (pid == 0) {
        res = p0;
    } else {
        float c = (pid == 2) ? (p0 - p1) : (p0 + p1);
        res = fminf(fmaxf(c, 0.0f), 1.0f);
    }
    out[b*(IM*IM) + n] = res;
}

extern "C" void kernel_launch(void* const* d_in, const int* in_sizes, int n_in,
                              void* d_out, int out_size, void* d_ws, size_t ws_size,
                              hipStream_t stream) {
    const int*   program_id    = (const int*)  d_in[0];
    const int*   shape_ids     = (const int*)  d_in[1];
    const float* raw_positions = (const float*)d_in[2];
    const float* w0            = (const float*)d_in[3];
    const float* b0            = (const float*)d_in[4];
    const float* w1            = (const float*)d_in[5];
    const float* b1            = (const float*)d_in[6];
    const float* w2            = (const float*)d_in[7];
    const float* b2            = (const float*)d_in[8];
    const float* w3            = (const float*)d_in[9];
    const float* b3            = (const float*)d_in[10];
    const float* lmr           = (const float*)d_in[11];
    float* out = (float*)d_out;

    dim3 grid(NBATCH * TILES);
    genmodel_kernel<<<grid, THREADS, 0, stream>>>(
        program_id, shape_ids, raw_positions,
        w0, b0, w1, b1, w2, b2, w3, b3, lmr, out);
}

// Round 2
// 197.396 us; speedup vs baseline: 2.6294x; 2.6294x over previous
//
#include <hip/hip_runtime.h>
#include <math.h>

#define IM 64
#define NBATCH 256
#define NS 2
#define NP 2
#define HID 64
#define THREADS 256

typedef _Float16 f16;
typedef _Float16 f16x8 __attribute__((ext_vector_type(8)));
typedef float    f32x4 __attribute__((ext_vector_type(4)));

// ---------------------------------------------------------------------------
// prep: wt[m][p][n][k] = (f16) w_m[p][k][n]   (m=0 -> w1, m=1 -> w2)
// B-fragment loads then read 8 contiguous k at row n: one dwordx4 per frag.
// ---------------------------------------------------------------------------
__global__ void prep_kernel(const float* __restrict__ w1,
                            const float* __restrict__ w2,
                            f16* __restrict__ wt) {
    int idx = blockIdx.x * blockDim.x + threadIdx.x;   // 0 .. 16383
    int m  = idx >> 13;
    int r  = idx & 8191;
    int p  = r >> 12;
    int nk = r & 4095;
    int n  = nk >> 6, k = nk & 63;
    const float* w = (m == 0) ? w1 : w2;
    wt[idx] = (f16)w[p*4096 + k*64 + n];
}

// ---------------------------------------------------------------------------
// main kernel: 1 block = 256 pixels of one image; wave w owns pixels
// [w*64, w*64+64) and a private 64x64 f16 LDS tile (XOR-swizzled rows).
// ---------------------------------------------------------------------------
__global__ __launch_bounds__(THREADS) void genmodel_kernel(
    const int*   __restrict__ program_id,
    const int*   __restrict__ shape_ids,
    const float* __restrict__ raw_positions,
    const float* __restrict__ g_w0, const float* __restrict__ g_b0,
    const float* __restrict__ g_b1, const float* __restrict__ g_b2,
    const float* __restrict__ g_w3, const float* __restrict__ g_b3,
    const float* __restrict__ g_lmr,
    const f16*   __restrict__ wt,          // prepped transposed f16 weights
    float* __restrict__ out)
{
    __shared__ f16 tile[4][HID*HID];       // 8 KB per wave, 32 KB total

    const int tid  = threadIdx.x;
    const int wave = tid >> 6;
    const int lane = tid & 63;
    const int u    = lane & 15;            // MFMA row/col-within-16
    const int g    = lane >> 4;            // MFMA k-group
    f16* tb = &tile[wave][0];

    const int b = blockIdx.x >> 4;
    const int n = ((blockIdx.x & 15) << 8) + tid;   // pixel index in image
    const int row = n >> 6, col = n & 63;
    const float cx = -1.0f + (2.0f/63.0f) * (float)col;
    const float cy = -1.0f + (2.0f/63.0f) * (float)row;

    float p0 = 0.0f, p1 = 0.0f;

    #pragma unroll 1
    for (int s = 0; s < NS; ++s) {
        const int pg = __builtin_amdgcn_readfirstlane(shape_ids[b*NS + s]);
        const float rx = raw_positions[(b*NS+s)*2 + 0];
        const float ry = raw_positions[(b*NS+s)*2 + 1];
        const float posx = 1.0f/(1.0f + expf(-rx)) - 0.5f;
        const float posy = 1.0f/(1.0f + expf(-ry)) - 0.5f;
        const float dx = cx - posx;
        const float dy = cy - posy;
        const float theta = atan2f(dy, dx);

        // ---- layer 0 (1->64) per-thread fp32, write own row (=lane) as f16
        {
            const float* w0  = g_w0 + pg*HID;
            const float* bb0 = g_b0 + pg*HID;
            #pragma unroll
            for (int c = 0; c < 8; ++c) {
                f16x8 v;
                #pragma unroll
                for (int i = 0; i < 8; ++i)
                    v[i] = (f16)fmaxf(fmaf(theta, w0[c*8+i], bb0[c*8+i]), 0.0f);
                const int e = lane*64 + ((c*8) ^ ((lane & 7) << 3));
                *(f16x8*)&tb[e] = v;
            }
        }
        __syncthreads();

        // ---- layers 1,2: 64x64 GEMM per wave via MFMA
        #pragma unroll
        for (int lay = 0; lay < 2; ++lay) {
            const f16*   W  = wt + lay*8192 + pg*4096;
            const float* bb = (lay == 0 ? g_b1 : g_b2) + pg*HID;

            // A fragments from swizzled tile: lane reads row 16*mt+u,
            // 8 contiguous k at 32*kh + 8*g.
            f16x8 af[4][2];
            #pragma unroll
            for (int mt = 0; mt < 4; ++mt)
                #pragma unroll
                for (int kh = 0; kh < 2; ++kh) {
                    const int r_ = 16*mt + u;
                    const int e  = r_*64 + ((32*kh + 8*g) ^ ((r_ & 7) << 3));
                    af[mt][kh] = *(const f16x8*)&tb[e];
                }

            f32x4 acc[4][4];
            #pragma unroll
            for (int nt = 0; nt < 4; ++nt) {
                const float bv = bb[16*nt + u];
                #pragma unroll
                for (int mt = 0; mt < 4; ++mt)
                    acc[mt][nt] = (f32x4){bv, bv, bv, bv};
            }

            #pragma unroll
            for (int nt = 0; nt < 4; ++nt)
                #pragma unroll
                for (int kh = 0; kh < 2; ++kh) {
                    const f16x8 bf = *(const f16x8*)&W[(16*nt + u)*64 + 32*kh + 8*g];
                    #pragma unroll
                    for (int mt = 0; mt < 4; ++mt)
                        acc[mt][nt] = __builtin_amdgcn_mfma_f32_16x16x32_f16(
                            af[mt][kh], bf, acc[mt][nt], 0, 0, 0);
                }

            __syncthreads();   // tile about to be overwritten

            // relu + scatter back to tile as f16 (C layout -> row-major tile)
            #pragma unroll
            for (int mt = 0; mt < 4; ++mt)
                #pragma unroll
                for (int nt = 0; nt < 4; ++nt)
                    #pragma unroll
                    for (int j = 0; j < 4; ++j) {
                        const float v  = fmaxf(acc[mt][nt][j], 0.0f);
                        const int  p_  = 16*mt + 4*g + j;
                        const int  c_  = 16*nt + u;
                        tb[p_*64 + (c_ ^ ((p_ & 7) << 3))] = (f16)v;
                    }
            __syncthreads();
        }

        // ---- head (64->1): per-thread dot of own row with w3
        {
            const float* w3 = g_w3 + pg*HID;
            float t0=0.f, t1=0.f, t2=0.f, t3=0.f;
            #pragma unroll
            for (int c = 0; c < 8; ++c) {
                const int e = lane*64 + ((c*8) ^ ((lane & 7) << 3));
                const f16x8 hv = *(const f16x8*)&tb[e];
                t0 = fmaf((float)hv[0], w3[c*8+0], t0);
                t1 = fmaf((float)hv[1], w3[c*8+1], t1);
                t2 = fmaf((float)hv[2], w3[c*8+2], t2);
                t3 = fmaf((float)hv[3], w3[c*8+3], t3);
                t0 = fmaf((float)hv[4], w3[c*8+4], t0);
                t1 = fmaf((float)hv[5], w3[c*8+5], t1);
                t2 = fmaf((float)hv[6], w3[c*8+6], t2);
                t3 = fmaf((float)hv[7], w3[c*8+7], t3);
            }
            const float ov = g_b3[pg] + ((t0+t1)+(t2+t3));

            const float mult  = expf(g_lmr[pg]);
            const float r2    = sqrtf(dx*dx + dy*dy);
            const float logit = mult * (expf(ov) - r2);
            const float p     = 1.0f / (1.0f + expf(-logit));
            if (s == 0) p0 = p; else p1 = p;
        }
        __syncthreads();   // before next shape's layer-0 writes
    }

    const int pid = program_id[b];
    float res;
    if (pid == 0) {
        res = p0;
    } else {
        float c = (pid == 2) ? (p0 - p1) : (p0 + p1);
        res = fminf(fmaxf(c, 0.0f), 1.0f);
    }
    out[b*(IM*IM) + n] = res;
}

extern "C" void kernel_launch(void* const* d_in, const int* in_sizes, int n_in,
                              void* d_out, int out_size, void* d_ws, size_t ws_size,
                              hipStream_t stream) {
    const int*   program_id    = (const int*)  d_in[0];
    const int*   shape_ids     = (const int*)  d_in[1];
    const float* raw_positions = (const float*)d_in[2];
    const float* w0            = (const float*)d_in[3];
    const float* b0            = (const float*)d_in[4];
    const float* w1            = (const float*)d_in[5];
    const float* b1            = (const float*)d_in[6];
    const float* w2            = (const float*)d_in[7];
    const float* b2            = (const float*)d_in[8];
    const float* w3            = (const float*)d_in[9];
    const float* b3            = (const float*)d_in[10];
    const float* lmr           = (const float*)d_in[11];
    float* out = (float*)d_out;
    f16*   wt  = (f16*)d_ws;               // 16384 f16 = 32 KB

    prep_kernel<<<64, 256, 0, stream>>>(w1, w2, wt);

    genmodel_kernel<<<NBATCH*16, THREADS, 0, stream>>>(
        program_id, shape_ids, raw_positions,
        w0, b0, b1, b2, w3, b3, lmr, wt, out);
}

// Round 3
// 77.082 us; speedup vs baseline: 6.7336x; 2.5609x over previous
//
#include <hip/hip_runtime.h>
#include <math.h>

#define IM 64
#define NBATCH 256
#define HID 64

typedef _Float16 f16;
typedef _Float16 f16x8 __attribute__((ext_vector_type(8)));
typedef _Float16 f16x4 __attribute__((ext_vector_type(4)));
typedef float    f32x4 __attribute__((ext_vector_type(4)));

// wt[m][p][n][k] = (f16) w_m[p][k][n]  (m=0 -> w1, m=1 -> w2); n=out-chan, k=in-chan
__global__ void prep_kernel(const float* __restrict__ w1,
                            const float* __restrict__ w2,
                            f16* __restrict__ wt) {
    int idx = blockIdx.x * 256 + threadIdx.x;   // 0 .. 16383
    int m  = idx >> 13;
    int r  = idx & 8191;
    int p  = r >> 12;
    int nk = r & 4095;
    int n  = nk >> 6, k = nk & 63;
    const float* w = m ? w2 : w1;
    wt[idx] = (f16)w[p*4096 + k*64 + n];
}

// 1 block = 1 wave = 64 pixels (one image row). Wave-private 8 KB LDS tile,
// NO barriers. tile[pixel][chan] f16 with XOR swizzle: elem = p*64 + (c ^ ((p&7)<<3)).
__global__ __launch_bounds__(64, 3) void genmodel_kernel(
    const int*   __restrict__ program_id,
    const int*   __restrict__ shape_ids,
    const float* __restrict__ raw_positions,
    const float* __restrict__ g_w0, const float* __restrict__ g_b0,
    const float* __restrict__ g_b1, const float* __restrict__ g_b2,
    const float* __restrict__ g_w3, const float* __restrict__ g_b3,
    const float* __restrict__ g_lmr,
    const f16*   __restrict__ wt,
    float* __restrict__ out)
{
    __shared__ f16 tile[HID*HID];            // 8 KB, wave-private

    const int lane = threadIdx.x;
    const int u = lane & 15, g = lane >> 4;  // MFMA index / k-group
    const int b    = blockIdx.x >> 6;
    const int irow = blockIdx.x & 63;        // image row

    const float cx = -1.0f + (2.0f/63.0f)*(float)lane;
    const float cy = -1.0f + (2.0f/63.0f)*(float)irow;

    const int pid = __builtin_amdgcn_readfirstlane(program_id[b]);
    const int ns  = (pid == 0) ? 1 : 2;      // skip shape 1 if unused

    float p0 = 0.f, p1 = 0.f;

    #pragma unroll 1
    for (int s = 0; s < ns; ++s) {
        const int pg = __builtin_amdgcn_readfirstlane(shape_ids[b*2 + s]);
        const float rx = raw_positions[(b*2+s)*2 + 0];
        const float ry = raw_positions[(b*2+s)*2 + 1];
        const float posx = 1.f/(1.f + expf(-rx)) - 0.5f;
        const float posy = 1.f/(1.f + expf(-ry)) - 0.5f;
        const float dx = cx - posx, dy = cy - posy;
        const float theta = atan2f(dy, dx);

        // ---- layer 0 (1->64): per-thread, write own pixel row (=lane)
        {
            const float* w0  = g_w0 + pg*HID;
            const float* bb0 = g_b0 + pg*HID;
            #pragma unroll
            for (int c = 0; c < 8; ++c) {
                f16x8 v;
                #pragma unroll
                for (int i = 0; i < 8; ++i)
                    v[i] = (f16)fmaxf(fmaf(theta, w0[c*8+i], bb0[c*8+i]), 0.f);
                *(f16x8*)&tile[lane*64 + ((c*8) ^ ((lane&7)<<3))] = v;
            }
        }

        // ---- layer 1: D[out-chan][pixel] = W1^T-fragments (A) x act (B)
        {
            f16x8 bf[4][2];                  // activations: pixel 16nt+u, k 32kh+8g
            #pragma unroll
            for (int nt = 0; nt < 4; ++nt)
                #pragma unroll
                for (int kh = 0; kh < 2; ++kh) {
                    const int p_ = 16*nt + u;
                    bf[nt][kh] = *(const f16x8*)&tile[p_*64 + ((32*kh + 8*g) ^ ((u&7)<<3))];
                }
            const f16* W1 = wt + pg*4096;
            #pragma unroll
            for (int mt = 0; mt < 4; ++mt) {
                const f16x8 wf0 = *(const f16x8*)&W1[(16*mt+u)*64 +      8*g];
                const f16x8 wf1 = *(const f16x8*)&W1[(16*mt+u)*64 + 32 + 8*g];
                const f32x4 bv  = *(const f32x4*)(g_b1 + pg*HID + 16*mt + 4*g);
                f32x4 acc[4];
                #pragma unroll
                for (int nt = 0; nt < 4; ++nt) acc[nt] = bv;
                #pragma unroll
                for (int nt = 0; nt < 4; ++nt) {
                    acc[nt] = __builtin_amdgcn_mfma_f32_16x16x32_f16(wf0, bf[nt][0], acc[nt], 0,0,0);
                    acc[nt] = __builtin_amdgcn_mfma_f32_16x16x32_f16(wf1, bf[nt][1], acc[nt], 0,0,0);
                }
                // lane owns pixel 16nt+u, chans 16mt+4g..+3 -> packed b64 write
                #pragma unroll
                for (int nt = 0; nt < 4; ++nt) {
                    f16x4 v;
                    v[0] = (f16)fmaxf(acc[nt][0], 0.f);
                    v[1] = (f16)fmaxf(acc[nt][1], 0.f);
                    v[2] = (f16)fmaxf(acc[nt][2], 0.f);
                    v[3] = (f16)fmaxf(acc[nt][3], 0.f);
                    const int p_ = 16*nt + u;
                    *(f16x4*)&tile[p_*64 + ((16*mt + 4*g) ^ ((u&7)<<3))] = v;
                }
            }
        }

        // ---- layer 2 + head fused: never materialize h2
        {
            f16x8 cf[4][2];
            #pragma unroll
            for (int nt = 0; nt < 4; ++nt)
                #pragma unroll
                for (int kh = 0; kh < 2; ++kh) {
                    const int p_ = 16*nt + u;
                    cf[nt][kh] = *(const f16x8*)&tile[p_*64 + ((32*kh + 8*g) ^ ((u&7)<<3))];
                }
            const f16* W2 = wt + 8192 + pg*4096;
            float hp[4] = {0.f, 0.f, 0.f, 0.f};
            #pragma unroll
            for (int mt = 0; mt < 4; ++mt) {
                const f16x8 wf0 = *(const f16x8*)&W2[(16*mt+u)*64 +      8*g];
                const f16x8 wf1 = *(const f16x8*)&W2[(16*mt+u)*64 + 32 + 8*g];
                const f32x4 bv  = *(const f32x4*)(g_b2 + pg*HID + 16*mt + 4*g);
                f32x4 acc[4];
                #pragma unroll
                for (int nt = 0; nt < 4; ++nt) acc[nt] = bv;
                #pragma unroll
                for (int nt = 0; nt < 4; ++nt) {
                    acc[nt] = __builtin_amdgcn_mfma_f32_16x16x32_f16(wf0, cf[nt][0], acc[nt], 0,0,0);
                    acc[nt] = __builtin_amdgcn_mfma_f32_16x16x32_f16(wf1, cf[nt][1], acc[nt], 0,0,0);
                }
                const f32x4 w3v = *(const f32x4*)(g_w3 + pg*HID + 16*mt + 4*g);
                #pragma unroll
                for (int nt = 0; nt < 4; ++nt) {
                    hp[nt] += fmaxf(acc[nt][0],0.f)*w3v[0] + fmaxf(acc[nt][1],0.f)*w3v[1]
                            + fmaxf(acc[nt][2],0.f)*w3v[2] + fmaxf(acc[nt][3],0.f)*w3v[3];
                }
            }
            // reduce over k-groups g (lanes u, u+16, u+32, u+48)
            #pragma unroll
            for (int nt = 0; nt < 4; ++nt) {
                hp[nt] += __shfl_xor(hp[nt], 16);
                hp[nt] += __shfl_xor(hp[nt], 32);
            }
            float ov = hp[0];
            if (g == 1) ov = hp[1];
            if (g == 2) ov = hp[2];
            if (g == 3) ov = hp[3];
            ov += g_b3[pg];

            const float mult  = expf(g_lmr[pg]);
            const float r2    = sqrtf(dx*dx + dy*dy);
            const float logit = mult * (expf(ov) - r2);
            const float p     = 1.f/(1.f + expf(-logit));
            if (s == 0) p0 = p; else p1 = p;
        }
    }

    float res;
    if (pid == 0) {
        res = p0;
    } else {
        float c = (pid == 2) ? (p0 - p1) : (p0 + p1);
        res = fminf(fmaxf(c, 0.f), 1.f);
    }
    out[b*(IM*IM) + irow*64 + lane] = res;
}

extern "C" void kernel_launch(void* const* d_in, const int* in_sizes, int n_in,
                              void* d_out, int out_size, void* d_ws, size_t ws_size,
                              hipStream_t stream) {
    const int*   program_id    = (const int*)  d_in[0];
    const int*   shape_ids     = (const int*)  d_in[1];
    const float* raw_positions = (const float*)d_in[2];
    const float* w0            = (const float*)d_in[3];
    const float* b0            = (const float*)d_in[4];
    const float* w1            = (const float*)d_in[5];
    const float* b1            = (const float*)d_in[6];
    const float* w2            = (const float*)d_in[7];
    const float* b2            = (const float*)d_in[8];
    const float* w3            = (const float*)d_in[9];
    const float* b3            = (const float*)d_in[10];
    const float* lmr           = (const float*)d_in[11];
    float* out = (float*)d_out;
    f16*   wt  = (f16*)d_ws;                 // 16384 f16 = 32 KB

    prep_kernel<<<64, 256, 0, stream>>>(w1, w2, wt);

    genmodel_kernel<<<NBATCH*64, 64, 0, stream>>>(
        program_id, shape_ids, raw_positions,
        w0, b0, b1, b2, w3, b3, lmr, wt, out);
}